// Round 3
// baseline (12285.367 us; speedup 1.0000x reference)
//
#include <hip/hip_runtime.h>
#include <hip/hip_bf16.h>
#include <math.h>

// ---------------------------------------------------------------------------
// DeepAR forward — split-fp16 MFMA version (round 3).
// Each GEMM operand x = hi + lo (two fp16); gates accumulate
//   ah*wh + ah*wl + al*wh  (3x mfma_f32_32x32x16_f16, fp32 acc)
// -> ~22-bit effective mantissa, i.e. fp32-quality GEMM, so the 128-step
// recurrence cannot amplify fp16 rounding into the 0.3 absmax seen in r2.
// Mask dtype autodetected (int32 vs uint8). Sampler fused into layer-2
// kernel via last-block atomic counter (3 launches/step + 2 setup).
// LDS: chunk-swizzled tiles (idx16B = c8*64 + (r^c8)) -> conflict-free
// ds_write_b128 staging AND conflict-free ds_read_b128 fragment reads.
// ---------------------------------------------------------------------------

#define BB   512
#define TT   128
#define COV  4
#define EMB  64
#define HIDN 512
#define G4   2048
#define XLD  128            // padded x row: [prev, cov(4), emb(64), 0...]
#define K0TOT (XLD + HIDN)  // 640
#define K12TOT (2*HIDN)     // 1024
#define LOG2PI 1.8378770664093453f

typedef _Float16 f16x8 __attribute__((ext_vector_type(8)));
typedef float f32x16 __attribute__((ext_vector_type(16)));

__device__ __forceinline__ float sigmoidf_(float x) { return 1.0f / (1.0f + expf(-x)); }
__device__ __forceinline__ float softplusf_(float x) {
    return fmaxf(x, 0.0f) + log1pf(expf(-fabsf(x)));
}
__device__ __forceinline__ void split2(float v, _Float16* hi, _Float16* lo) {
    _Float16 h = (_Float16)v;
    *hi = h;
    *lo = (_Float16)(v - (float)h);
}

// ---------------------------------------------------------------------------
// Pack weights into hi/lo fp16 pairs, rows interleaved g' = j*4 + q.
// W0[g'][640] = [Wih0(69) | 0 | Whh0(512)]; W1/2[g'][1024] = [Wih|Whh].
// biasI[l][g'] = b_ih + b_hh (fp32).
// ---------------------------------------------------------------------------
__global__ __launch_bounds__(256) void pack_weights_split(
    const float* __restrict__ Wih0, const float* __restrict__ Whh0,
    const float* __restrict__ Wih1, const float* __restrict__ Whh1,
    const float* __restrict__ Wih2, const float* __restrict__ Whh2,
    const float* __restrict__ bih0, const float* __restrict__ bhh0,
    const float* __restrict__ bih1, const float* __restrict__ bhh1,
    const float* __restrict__ bih2, const float* __restrict__ bhh2,
    _Float16* __restrict__ W0h, _Float16* __restrict__ W0l,
    _Float16* __restrict__ W1h, _Float16* __restrict__ W1l,
    _Float16* __restrict__ W2h, _Float16* __restrict__ W2l,
    float* __restrict__ biasI)
{
    const int N0 = G4 * K0TOT;       // 2048*640
    const int N1 = G4 * K12TOT;      // 2048*1024
    const int total = N0 + 2 * N1 + 3 * G4;
    for (int i = blockIdx.x * blockDim.x + threadIdx.x; i < total;
         i += gridDim.x * blockDim.x) {
        if (i < N0) {
            int gp = i / K0TOT, k = i - gp * K0TOT;
            int orig = ((gp & 3) << 9) + (gp >> 2);   // q*512 + j
            float v = 0.0f;
            if (k < 69)        v = Wih0[orig * 69 + k];
            else if (k >= XLD) v = Whh0[orig * HIDN + (k - XLD)];
            split2(v, &W0h[i], &W0l[i]);
        } else if (i < N0 + N1) {
            int m = i - N0;
            int gp = m >> 10, k = m & 1023;
            int orig = ((gp & 3) << 9) + (gp >> 2);
            float v = (k < HIDN) ? Wih1[orig * HIDN + k] : Whh1[orig * HIDN + (k - HIDN)];
            split2(v, &W1h[m], &W1l[m]);
        } else if (i < N0 + 2 * N1) {
            int m = i - N0 - N1;
            int gp = m >> 10, k = m & 1023;
            int orig = ((gp & 3) << 9) + (gp >> 2);
            float v = (k < HIDN) ? Wih2[orig * HIDN + k] : Whh2[orig * HIDN + (k - HIDN)];
            split2(v, &W2h[m], &W2l[m]);
        } else {
            int m = i - N0 - 2 * N1;                  // 0..6143
            int l = m >> 11, gp = m & 2047;
            int orig = ((gp & 3) << 9) + (gp >> 2);
            const float* bi = (l == 0) ? bih0 : ((l == 1) ? bih1 : bih2);
            const float* bh = (l == 0) ? bhh0 : ((l == 1) ? bhh1 : bhh2);
            biasI[m] = bi[orig] + bh[orig];
        }
    }
}

// ---------------------------------------------------------------------------
// State init. Hh/Hl: 6 planes each (2 ping-pong x 3 layers). C: 3 f32 planes.
// xdyn hi/lo. params/totcnt/donecnt zero. Mask encoding detection:
// word0 in {0,1} -> int32 bools, else (e.g. 0x01010101) -> byte bools.
// ---------------------------------------------------------------------------
__global__ __launch_bounds__(256) void init_state(
    const float* __restrict__ cov, const int* __restrict__ idx,
    const float* __restrict__ emb_table, const int* __restrict__ maskbuf,
    _Float16* __restrict__ Hh, _Float16* __restrict__ Hl,
    float* __restrict__ C, _Float16* __restrict__ xdh, _Float16* __restrict__ xdl,
    float* __restrict__ params, float* __restrict__ totcnt,
    int* __restrict__ donecnt, int* __restrict__ maskmode)
{
    const int PL = BB * HIDN;
    const int NH = 6 * PL;
    const int NC = 3 * PL;
    const int NX = BB * XLD;
    const int total = 2 * NH + NC + 2 * NX + 2 * BB + 2;
    int gtid = blockIdx.x * blockDim.x + threadIdx.x;
    if (gtid == 0) {
        *donecnt = 0;
        int w0 = maskbuf[0];
        *maskmode = (w0 == 0 || w0 == 1) ? 0 : 1;   // 0 = int32, 1 = bytes
    }
    for (int i = gtid; i < total; i += gridDim.x * blockDim.x) {
        if (i < NH)            Hh[i] = (_Float16)0.0f;
        else if (i < 2 * NH)   Hl[i - NH] = (_Float16)0.0f;
        else if (i < 2 * NH + NC) C[i - 2 * NH] = 0.0f;
        else if (i < 2 * NH + NC + 2 * NX) {
            int m = i - 2 * NH - NC;
            int isLo = (m >= NX); if (isLo) m -= NX;
            int b = m >> 7, k = m & 127;
            float v = 0.0f;
            if (k >= 1 && k < 1 + COV)      v = cov[(b * TT + 0) * COV + (k - 1)];
            else if (k >= 5 && k < 5 + EMB) v = emb_table[idx[b] * EMB + (k - 5)];
            _Float16 h = (_Float16)v;
            if (!isLo) xdh[m] = h;
            else       xdl[m] = (_Float16)(v - (float)h);
        } else {
            int m = i - 2 * NH - NC - 2 * NX;
            if (m < 2 * BB) params[m] = 0.0f;
            else            totcnt[m - 2 * BB] = 0.0f;
        }
    }
}

// ---------------------------------------------------------------------------
// Fused LSTM layer, split-fp16: gates = A*W^T (3 MFMAs per frag pair),
// LDS gate-bounce, cell update, split-h write, fc partial + fused sampler
// (last finishing block) when isLast.
// Tile 64(b) x 64(g'), 4 waves 2x2 each 32x32, BK=64. Grid (8, 32).
// LDS tiles in chunk-swizzled layout: 16B-chunk index = c8*64 + (r ^ c8).
// ---------------------------------------------------------------------------
__global__ __launch_bounds__(256, 1) void lstm_layer(
    const _Float16* __restrict__ A0h, const _Float16* __restrict__ A0l,
    int ldA0, int k0len,
    const _Float16* __restrict__ A1h, const _Float16* __restrict__ A1l,
    int ldA1, int kTot,
    const _Float16* __restrict__ Wh, const _Float16* __restrict__ Wl,
    const float* __restrict__ biasI,
    float* __restrict__ cPlane,
    _Float16* __restrict__ hOutH, _Float16* __restrict__ hOutL,
    int isLast, int t,
    float* __restrict__ params, const float* __restrict__ fcw,
    const float* __restrict__ fcb,
    const float* __restrict__ target, const float* __restrict__ cov,
    const void* __restrict__ maskraw, const float* __restrict__ noise,
    _Float16* __restrict__ xdh, _Float16* __restrict__ xdl,
    float* __restrict__ totcnt, float* __restrict__ out,
    int* __restrict__ donecnt, const int* __restrict__ maskmode)
{
    __shared__ __align__(16) _Float16 sm[4 * 4096];   // Ah|Al|Bh|Bl, 32 KiB
    _Float16* Ahs = sm;
    _Float16* Als = sm + 4096;
    _Float16* Bhs = sm + 8192;
    _Float16* Bls = sm + 12288;
    float* gbuf = (float*)sm;                          // [64][68] alias, used after

    const int tid  = threadIdx.x;
    const int lane = tid & 63;
    const int wv   = tid >> 6;
    const int wr   = wv >> 1;
    const int wc   = wv & 1;
    const int b0   = blockIdx.x << 6;
    const int g0   = blockIdx.y << 6;

    f32x16 acc = {0.0f};

    const int rA = (wr << 5) + (lane & 31);   // A row in tile
    const int rB = (wc << 5) + (lane & 31);   // B row (g') in tile
    const int hi = lane >> 5;                 // k-half select

    for (int kt = 0; kt < kTot; kt += 64) {
        #pragma unroll
        for (int it = 0; it < 2; ++it) {
            int s  = (it << 8) + tid;          // 0..511
            int r  = s >> 3;                   // row 0..63
            int c8 = s & 7;                    // 8-f16 chunk
            int k  = kt + (c8 << 3);
            int dst = ((c8 << 6) + (r ^ c8)) << 3;   // swizzled f16 index
            const _Float16 *ph, *pl;
            if (k < k0len) {
                size_t off = (size_t)(b0 + r) * ldA0 + k;
                ph = A0h + off; pl = A0l + off;
            } else {
                size_t off = (size_t)(b0 + r) * ldA1 + (k - k0len);
                ph = A1h + off; pl = A1l + off;
            }
            *(f16x8*)(Ahs + dst) = *(const f16x8*)ph;
            *(f16x8*)(Als + dst) = *(const f16x8*)pl;
            size_t woff = (size_t)(g0 + r) * kTot + k;
            *(f16x8*)(Bhs + dst) = *(const f16x8*)(Wh + woff);
            *(f16x8*)(Bls + dst) = *(const f16x8*)(Wl + woff);
        }
        __syncthreads();
        #pragma unroll
        for (int ks = 0; ks < 4; ++ks) {
            int ca = (ks << 1) + hi;                      // chunk for this k-half
            int aIdx = ((ca << 6) + (rA ^ ca)) << 3;
            int bIdx = ((ca << 6) + (rB ^ ca)) << 3;
            f16x8 fah = *(const f16x8*)(Ahs + aIdx);
            f16x8 fal = *(const f16x8*)(Als + aIdx);
            f16x8 fbh = *(const f16x8*)(Bhs + bIdx);
            f16x8 fbl = *(const f16x8*)(Bls + bIdx);
            acc = __builtin_amdgcn_mfma_f32_32x32x16_f16(fal, fbh, acc, 0, 0, 0);
            acc = __builtin_amdgcn_mfma_f32_32x32x16_f16(fah, fbl, acc, 0, 0, 0);
            acc = __builtin_amdgcn_mfma_f32_32x32x16_f16(fah, fbh, acc, 0, 0, 0);
        }
        __syncthreads();
    }

    // ---- bounce acc -> gbuf. C/D: col=lane&31, row=(r&3)+8*(r>>2)+4*(lane>>5)
    {
        const int col = (wc << 5) + (lane & 31);
        const int rb  = (wr << 5) + (hi << 2);
        #pragma unroll
        for (int r = 0; r < 16; ++r) {
            int row = rb + (r & 3) + ((r >> 2) << 3);
            gbuf[row * 68 + col] = acc[r];
        }
    }
    __syncthreads();

    // ---- cell update: thread -> (j_local = tid&15, 4 b-rows)
    {
        const int jl = tid & 15;
        const int bq = tid >> 4;                 // 0..15
        const int jg = (blockIdx.y << 4) + jl;   // global j in [0,512)
        const float4 bv = *(const float4*)&biasI[g0 + (jl << 2)];
        float f0 = 0.0f, f1 = 0.0f;
        if (isLast) { f0 = fcw[jg]; f1 = fcw[HIDN + jg]; }

        #pragma unroll
        for (int i = 0; i < 4; ++i) {
            const int b  = (bq << 2) + i;
            const int gb = b0 + b;
            const float4 gv = *(const float4*)&gbuf[b * 68 + (jl << 2)];
            float ig = sigmoidf_(gv.x + bv.x);
            float fg = sigmoidf_(gv.y + bv.y);
            float gg = tanhf(gv.z + bv.z);
            float og = sigmoidf_(gv.w + bv.w);
            float cold = cPlane[(size_t)gb * HIDN + jg];
            float cnew = fg * cold + ig * gg;
            float hnew = og * tanhf(cnew);
            cPlane[(size_t)gb * HIDN + jg] = cnew;
            split2(hnew, &hOutH[(size_t)gb * HIDN + jg], &hOutL[(size_t)gb * HIDN + jg]);
            if (isLast) {
                float v0 = hnew * f0, v1 = hnew * f1;
                #pragma unroll
                for (int off = 8; off > 0; off >>= 1) {
                    v0 += __shfl_down(v0, off, 16);
                    v1 += __shfl_down(v1, off, 16);
                }
                if (jl == 0) {
                    atomicAdd(&params[gb * 2 + 0], v0);
                    atomicAdd(&params[gb * 2 + 1], v1);
                }
            }
        }
    }

    // ---- fused sampler: the last block to finish runs the per-step tail
    if (isLast) {
        __shared__ int lastf;
        __syncthreads();           // all this block's atomics complete
        __threadfence();
        if (tid == 0) lastf = (atomicAdd(donecnt, 1) == 255);
        __syncthreads();
        if (lastf) {
            __threadfence();       // acquire: see all 256 blocks' params adds
            __shared__ float red[8];
            const int mm = *maskmode;
            const float fb0 = fcb[0], fb1 = fcb[1];
            float v0a = 0.0f, v1a = 0.0f;
            #pragma unroll
            for (int half = 0; half < 2; ++half) {
                const int b = tid + (half << 8);
                float mean  = params[b * 2 + 0] + fb0;
                float sigma = softplusf_(params[b * 2 + 1] + fb1) + 1e-6f;
                out[1 + t * BB + b]           = mean;
                out[1 + TT * BB + t * BB + b] = sigma;
                float z = target[b * TT + t];
                float obs = mm
                    ? (((const unsigned char*)maskraw)[b * TT + t] ? 1.0f : 0.0f)
                    : (((const int*)maskraw)[b * TT + t] ? 1.0f : 0.0f);
                float nv = noise[t * BB + b];
                float dz = (z - mean) / sigma;
                float nll = 0.5f * LOG2PI + logf(sigma) + 0.5f * dz * dz;
                v0a += nll * obs;
                v1a += obs;
                params[b * 2 + 0] = 0.0f;    // re-zero for next step
                params[b * 2 + 1] = 0.0f;
                float sample = mean + sigma * nv;
                float nxt = (obs != 0.0f) ? z : sample;
                if (t + 1 < TT) split2(nxt, &xdh[b * XLD + 0], &xdl[b * XLD + 0]);
            }
            #pragma unroll
            for (int off = 32; off > 0; off >>= 1) {
                v0a += __shfl_down(v0a, off);
                v1a += __shfl_down(v1a, off);
            }
            if ((tid & 63) == 0) { red[(tid >> 6) * 2] = v0a; red[(tid >> 6) * 2 + 1] = v1a; }
            __syncthreads();
            if (tid == 0) {
                float s = 0.0f, so = 0.0f;
                #pragma unroll
                for (int w = 0; w < 4; ++w) { s += red[w * 2]; so += red[w * 2 + 1]; }
                float sl = (so > 0.0f) ? (s / fmaxf(so, 1.0f)) : 0.0f;
                totcnt[0] += sl;
                totcnt[1] += (so > 0.0f) ? 1.0f : 0.0f;
                if (t == TT - 1)
                    out[0] = (totcnt[1] > 0.0f) ? (totcnt[0] / totcnt[1]) : totcnt[0];
                atomicExch(donecnt, 0);      // reset for next step
            }
            // covariates for t+1 (emb section is static, written by init)
            if (t + 1 < TT) {
                for (int m = tid; m < BB * COV; m += 256) {
                    int bb = m >> 2, k = m & 3;
                    split2(cov[(bb * TT + (t + 1)) * COV + k],
                           &xdh[bb * XLD + 1 + k], &xdl[bb * XLD + 1 + k]);
                }
            }
        }
    }
}

// ---------------------------------------------------------------------------
extern "C" void kernel_launch(void* const* d_in, const int* in_sizes, int n_in,
                              void* d_out, int out_size, void* d_ws, size_t ws_size,
                              hipStream_t stream) {
    const float* target       = (const float*)d_in[0];
    const float* covariates   = (const float*)d_in[1];
    const void*  maskraw      = d_in[2];
    const int*   idx          = (const int*)d_in[3];
    const float* emb_table    = (const float*)d_in[4];
    const float* fc_w         = (const float*)d_in[5];
    const float* fc_b         = (const float*)d_in[6];
    const float* noise        = (const float*)d_in[7];
    const float* Wih0 = (const float*)d_in[8];
    const float* Whh0 = (const float*)d_in[9];
    const float* bih0 = (const float*)d_in[10];
    const float* bhh0 = (const float*)d_in[11];
    const float* Wih1 = (const float*)d_in[12];
    const float* Whh1 = (const float*)d_in[13];
    const float* bih1 = (const float*)d_in[14];
    const float* bhh1 = (const float*)d_in[15];
    const float* Wih2 = (const float*)d_in[16];
    const float* Whh2 = (const float*)d_in[17];
    const float* bih2 = (const float*)d_in[18];
    const float* bhh2 = (const float*)d_in[19];
    (void)in_sizes; (void)n_in; (void)ws_size;

    const size_t PLANE = (size_t)BB * HIDN;
    const size_t NW0 = (size_t)G4 * K0TOT;     // 1,310,720
    const size_t NW1 = (size_t)G4 * K12TOT;    // 2,097,152

    _Float16* p = (_Float16*)d_ws;
    _Float16* W0h = p; p += NW0;
    _Float16* W0l = p; p += NW0;
    _Float16* W1h = p; p += NW1;
    _Float16* W1l = p; p += NW1;
    _Float16* W2h = p; p += NW1;
    _Float16* W2l = p; p += NW1;
    _Float16* Hh  = p; p += 6 * PLANE;
    _Float16* Hl  = p; p += 6 * PLANE;
    _Float16* xdh = p; p += (size_t)BB * XLD;
    _Float16* xdl = p; p += (size_t)BB * XLD;
    float* fp = (float*)p;
    float* biasI  = fp; fp += 3 * G4;
    float* C      = fp; fp += 3 * PLANE;
    float* params = fp; fp += 2 * BB;
    float* totcnt = fp; fp += 2;
    int* ip = (int*)fp;
    int* donecnt  = ip;
    int* maskmode = ip + 1;

    float* out = (float*)d_out; (void)out_size;

    pack_weights_split<<<1024, 256, 0, stream>>>(
        Wih0, Whh0, Wih1, Whh1, Wih2, Whh2,
        bih0, bhh0, bih1, bhh1, bih2, bhh2,
        W0h, W0l, W1h, W1l, W2h, W2l, biasI);
    init_state<<<1024, 256, 0, stream>>>(
        covariates, idx, emb_table, (const int*)maskraw,
        Hh, Hl, C, xdh, xdl, params, totcnt, donecnt, maskmode);

    dim3 ggrid(8, 32);
    for (int t = 0; t < TT; ++t) {
        int pi = t & 1;
        size_t curo = (pi ? 3 : 0) * PLANE;
        size_t nxto = (pi ? 0 : 3) * PLANE;
        _Float16* H0ch = Hh + curo;             _Float16* H0cl = Hl + curo;
        _Float16* H1ch = H0ch + PLANE;          _Float16* H1cl = H0cl + PLANE;
        _Float16* H2ch = H1ch + PLANE;          _Float16* H2cl = H1cl + PLANE;
        _Float16* H0nh = Hh + nxto;             _Float16* H0nl = Hl + nxto;
        _Float16* H1nh = H0nh + PLANE;          _Float16* H1nl = H0nl + PLANE;
        _Float16* H2nh = H1nh + PLANE;          _Float16* H2nl = H1nl + PLANE;

        // Layer 0: A = [xdyn(128) | h0_cur(512)], K=640
        lstm_layer<<<ggrid, 256, 0, stream>>>(
            xdh, xdl, XLD, XLD, H0ch, H0cl, HIDN, K0TOT,
            W0h, W0l, biasI + 0 * G4, C + 0 * PLANE, H0nh, H0nl,
            0, t, params, fc_w, fc_b, target, covariates, maskraw, noise,
            xdh, xdl, totcnt, out, donecnt, maskmode);
        // Layer 1: A = [h0_new | h1_cur], K=1024
        lstm_layer<<<ggrid, 256, 0, stream>>>(
            H0nh, H0nl, HIDN, HIDN, H1ch, H1cl, HIDN, K12TOT,
            W1h, W1l, biasI + 1 * G4, C + 1 * PLANE, H1nh, H1nl,
            0, t, params, fc_w, fc_b, target, covariates, maskraw, noise,
            xdh, xdl, totcnt, out, donecnt, maskmode);
        // Layer 2: A = [h1_new | h2_cur], K=1024, + fc partials + fused sampler
        lstm_layer<<<ggrid, 256, 0, stream>>>(
            H1nh, H1nl, HIDN, HIDN, H2ch, H2cl, HIDN, K12TOT,
            W2h, W2l, biasI + 2 * G4, C + 2 * PLANE, H2nh, H2nl,
            1, t, params, fc_w, fc_b, target, covariates, maskraw, noise,
            xdh, xdl, totcnt, out, donecnt, maskmode);
    }
}

// Round 5
// 10573.833 us; speedup vs baseline: 1.1619x; 1.1619x over previous
//
#include <hip/hip_runtime.h>
#include <hip/hip_bf16.h>
#include <math.h>

// ---------------------------------------------------------------------------
// DeepAR forward — split-fp16 MFMA, round 5 (= round 4 resubmitted; r4 never
// ran: GPU acquisition timeout). r3 passed (absmax 3.9e-3) at 12.28 ms.
// This kernel attacks the 4x gap to the DS floor:
//  * 512-thread blocks, split-K x2 (wave groups on alternating 64-k subtiles),
//    128-k staging rounds -> 2 waves/SIMD occupancy, half the barriers.
//  * register prefetch of next round's global loads (latency hides under MFMA)
//  * XCD panel swizzle: all 8 b-tile blocks of a g-panel on one XCD ->
//    B panels + A become L2-resident (3 MB/XCD), LLC traffic 128->24 MB/GEMM.
// Predicted: 12.28 -> ~4-5.5 ms.
// ---------------------------------------------------------------------------

#define BB   512
#define TT   128
#define COV  4
#define EMB  64
#define HIDN 512
#define G4   2048
#define XLD  128            // padded x row: [prev, cov(4), emb(64), 0...]
#define K0TOT (XLD + HIDN)  // 640  (5 rounds of 128)
#define K12TOT (2*HIDN)     // 1024 (8 rounds of 128)
#define LOG2PI 1.8378770664093453f

typedef _Float16 f16x8 __attribute__((ext_vector_type(8)));
typedef float f32x16 __attribute__((ext_vector_type(16)));

__device__ __forceinline__ float sigmoidf_(float x) { return 1.0f / (1.0f + expf(-x)); }
__device__ __forceinline__ float softplusf_(float x) {
    return fmaxf(x, 0.0f) + log1pf(expf(-fabsf(x)));
}
__device__ __forceinline__ void split2(float v, _Float16* hi, _Float16* lo) {
    _Float16 h = (_Float16)v;
    *hi = h;
    *lo = (_Float16)(v - (float)h);
}

// ---------------------------------------------------------------------------
// Pack weights into hi/lo fp16 pairs, rows interleaved g' = j*4 + q.
// ---------------------------------------------------------------------------
__global__ __launch_bounds__(256) void pack_weights_split(
    const float* __restrict__ Wih0, const float* __restrict__ Whh0,
    const float* __restrict__ Wih1, const float* __restrict__ Whh1,
    const float* __restrict__ Wih2, const float* __restrict__ Whh2,
    const float* __restrict__ bih0, const float* __restrict__ bhh0,
    const float* __restrict__ bih1, const float* __restrict__ bhh1,
    const float* __restrict__ bih2, const float* __restrict__ bhh2,
    _Float16* __restrict__ W0h, _Float16* __restrict__ W0l,
    _Float16* __restrict__ W1h, _Float16* __restrict__ W1l,
    _Float16* __restrict__ W2h, _Float16* __restrict__ W2l,
    float* __restrict__ biasI)
{
    const int N0 = G4 * K0TOT;
    const int N1 = G4 * K12TOT;
    const int total = N0 + 2 * N1 + 3 * G4;
    for (int i = blockIdx.x * blockDim.x + threadIdx.x; i < total;
         i += gridDim.x * blockDim.x) {
        if (i < N0) {
            int gp = i / K0TOT, k = i - gp * K0TOT;
            int orig = ((gp & 3) << 9) + (gp >> 2);   // q*512 + j
            float v = 0.0f;
            if (k < 69)        v = Wih0[orig * 69 + k];
            else if (k >= XLD) v = Whh0[orig * HIDN + (k - XLD)];
            split2(v, &W0h[i], &W0l[i]);
        } else if (i < N0 + N1) {
            int m = i - N0;
            int gp = m >> 10, k = m & 1023;
            int orig = ((gp & 3) << 9) + (gp >> 2);
            float v = (k < HIDN) ? Wih1[orig * HIDN + k] : Whh1[orig * HIDN + (k - HIDN)];
            split2(v, &W1h[m], &W1l[m]);
        } else if (i < N0 + 2 * N1) {
            int m = i - N0 - N1;
            int gp = m >> 10, k = m & 1023;
            int orig = ((gp & 3) << 9) + (gp >> 2);
            float v = (k < HIDN) ? Wih2[orig * HIDN + k] : Whh2[orig * HIDN + (k - HIDN)];
            split2(v, &W2h[m], &W2l[m]);
        } else {
            int m = i - N0 - 2 * N1;
            int l = m >> 11, gp = m & 2047;
            int orig = ((gp & 3) << 9) + (gp >> 2);
            const float* bi = (l == 0) ? bih0 : ((l == 1) ? bih1 : bih2);
            const float* bh = (l == 0) ? bhh0 : ((l == 1) ? bhh1 : bhh2);
            biasI[m] = bi[orig] + bh[orig];
        }
    }
}

// ---------------------------------------------------------------------------
// State init. Mask encoding autodetect (int32 vs bytes).
// ---------------------------------------------------------------------------
__global__ __launch_bounds__(256) void init_state(
    const float* __restrict__ cov, const int* __restrict__ idx,
    const float* __restrict__ emb_table, const int* __restrict__ maskbuf,
    _Float16* __restrict__ Hh, _Float16* __restrict__ Hl,
    float* __restrict__ C, _Float16* __restrict__ xdh, _Float16* __restrict__ xdl,
    float* __restrict__ params, float* __restrict__ totcnt,
    int* __restrict__ donecnt, int* __restrict__ maskmode)
{
    const int PL = BB * HIDN;
    const int NH = 6 * PL;
    const int NC = 3 * PL;
    const int NX = BB * XLD;
    const int total = 2 * NH + NC + 2 * NX + 2 * BB + 2;
    int gtid = blockIdx.x * blockDim.x + threadIdx.x;
    if (gtid == 0) {
        *donecnt = 0;
        int w0 = maskbuf[0];
        *maskmode = (w0 == 0 || w0 == 1) ? 0 : 1;   // 0 = int32, 1 = bytes
    }
    for (int i = gtid; i < total; i += gridDim.x * blockDim.x) {
        if (i < NH)            Hh[i] = (_Float16)0.0f;
        else if (i < 2 * NH)   Hl[i - NH] = (_Float16)0.0f;
        else if (i < 2 * NH + NC) C[i - 2 * NH] = 0.0f;
        else if (i < 2 * NH + NC + 2 * NX) {
            int m = i - 2 * NH - NC;
            int isLo = (m >= NX); if (isLo) m -= NX;
            int b = m >> 7, k = m & 127;
            float v = 0.0f;
            if (k >= 1 && k < 1 + COV)      v = cov[(b * TT + 0) * COV + (k - 1)];
            else if (k >= 5 && k < 5 + EMB) v = emb_table[idx[b] * EMB + (k - 5)];
            _Float16 h = (_Float16)v;
            if (!isLo) xdh[m] = h;
            else       xdl[m] = (_Float16)(v - (float)h);
        } else {
            int m = i - 2 * NH - NC - 2 * NX;
            if (m < 2 * BB) params[m] = 0.0f;
            else            totcnt[m - 2 * BB] = 0.0f;
        }
    }
}

// ---------------------------------------------------------------------------
// Fused LSTM layer, split-fp16, 8 waves, split-K x2, reg-prefetch staging.
// Tile 64(b) x 64(g'). Wave w: kh = w>>2 (k subtile), (wr,wc) = 2x2 of w&3.
// Grid: 256 blocks 1-D, XCD panel swizzle:
//   fid -> g = ((fid>>6)<<3)|(fid&7), btile = (fid>>3)&7  (fid%8 == g%8)
// LDS: Ah|Al|Bh|Bl each [2 subtiles][64 rows][64 k] chunk-swizzled
//   (16B-chunk idx = sub*512 + c8*64 + (row ^ c8)), 64 KiB total.
// ---------------------------------------------------------------------------
__global__ __launch_bounds__(512, 1) void lstm_layer(
    const _Float16* __restrict__ A0h, const _Float16* __restrict__ A0l,
    int ldA0, int k0len,
    const _Float16* __restrict__ A1h, const _Float16* __restrict__ A1l,
    int ldA1, int kTot,
    const _Float16* __restrict__ Wh, const _Float16* __restrict__ Wl,
    const float* __restrict__ biasI,
    float* __restrict__ cPlane,
    _Float16* __restrict__ hOutH, _Float16* __restrict__ hOutL,
    int isLast, int t,
    float* __restrict__ params, const float* __restrict__ fcw,
    const float* __restrict__ fcb,
    const float* __restrict__ target, const float* __restrict__ cov,
    const void* __restrict__ maskraw, const float* __restrict__ noise,
    _Float16* __restrict__ xdh, _Float16* __restrict__ xdl,
    float* __restrict__ totcnt, float* __restrict__ out,
    int* __restrict__ donecnt, const int* __restrict__ maskmode)
{
    __shared__ __align__(16) _Float16 sm[4 * 8192];   // 64 KiB
    _Float16* Ahs = sm;
    _Float16* Als = sm + 8192;
    _Float16* Bhs = sm + 16384;
    _Float16* Bls = sm + 24576;
    float* gbuf = (float*)sm;                          // [64][68] alias

    const int tid  = threadIdx.x;
    const int lane = tid & 63;
    const int wv4  = (tid >> 6) & 3;
    const int kh   = tid >> 8;                // k-subtile group (0/1)
    const int wr   = wv4 >> 1;
    const int wc   = wv4 & 1;

    // XCD panel swizzle
    const int fid = blockIdx.x;
    const int g   = ((fid >> 6) << 3) | (fid & 7);   // panel 0..31
    const int b0  = ((fid >> 3) & 7) << 6;           // b-tile base
    const int g0  = g << 6;                          // g' base

    f32x16 acc = {0.0f};

    const int rA = (wr << 5) + (lane & 31);
    const int rB = (wc << 5) + (lane & 31);
    const int hi = lane >> 5;

    const int R = kTot >> 7;                  // rounds of 128 k

    // staging indices for this thread (2 chunks per array per round)
    int srow[2], sc16[2], sdst[2];
    #pragma unroll
    for (int it = 0; it < 2; ++it) {
        int idx = (it << 9) + tid;            // 0..1023
        srow[it] = idx >> 4;                  // row 0..63
        sc16[it] = idx & 15;                  // 16B chunk 0..15 (k = c16*8)
        int sub = sc16[it] >> 3, c8 = sc16[it] & 7;
        sdst[it] = ((sub << 9) + (c8 << 6) + (srow[it] ^ c8)) << 3;
    }

    f16x8 pAh[2], pAl[2], pBh[2], pBl[2];

    // prefetch round 0
    #pragma unroll
    for (int it = 0; it < 2; ++it) {
        int k = sc16[it] << 3;
        const _Float16 *ph, *pl;
        if (k < k0len) {
            size_t off = (size_t)(b0 + srow[it]) * ldA0 + k;
            ph = A0h + off; pl = A0l + off;
        } else {
            size_t off = (size_t)(b0 + srow[it]) * ldA1 + (k - k0len);
            ph = A1h + off; pl = A1l + off;
        }
        pAh[it] = *(const f16x8*)ph;
        pAl[it] = *(const f16x8*)pl;
        size_t woff = (size_t)(g0 + srow[it]) * kTot + k;
        pBh[it] = *(const f16x8*)(Wh + woff);
        pBl[it] = *(const f16x8*)(Wl + woff);
    }

    for (int r = 0; r < R; ++r) {
        // write staged regs -> LDS
        #pragma unroll
        for (int it = 0; it < 2; ++it) {
            *(f16x8*)(Ahs + sdst[it]) = pAh[it];
            *(f16x8*)(Als + sdst[it]) = pAl[it];
            *(f16x8*)(Bhs + sdst[it]) = pBh[it];
            *(f16x8*)(Bls + sdst[it]) = pBl[it];
        }
        __syncthreads();

        // prefetch round r+1 (issue before compute; latency hides under MFMA)
        if (r + 1 < R) {
            int kt = (r + 1) << 7;
            #pragma unroll
            for (int it = 0; it < 2; ++it) {
                int k = kt + (sc16[it] << 3);
                const _Float16 *ph, *pl;
                if (k < k0len) {
                    size_t off = (size_t)(b0 + srow[it]) * ldA0 + k;
                    ph = A0h + off; pl = A0l + off;
                } else {
                    size_t off = (size_t)(b0 + srow[it]) * ldA1 + (k - k0len);
                    ph = A1h + off; pl = A1l + off;
                }
                pAh[it] = *(const f16x8*)ph;
                pAl[it] = *(const f16x8*)pl;
                size_t woff = (size_t)(g0 + srow[it]) * kTot + k;
                pBh[it] = *(const f16x8*)(Wh + woff);
                pBl[it] = *(const f16x8*)(Wl + woff);
            }
        }

        // compute this wave group's 64-k subtile
        const int sbase = kh << 9;            // chunk offset of subtile
        #pragma unroll
        for (int ks = 0; ks < 4; ++ks) {
            int ca = (ks << 1) + hi;
            int aIdx = ((sbase + (ca << 6) + (rA ^ ca))) << 3;
            int bIdx = ((sbase + (ca << 6) + (rB ^ ca))) << 3;
            f16x8 fah = *(const f16x8*)(Ahs + aIdx);
            f16x8 fal = *(const f16x8*)(Als + aIdx);
            f16x8 fbh = *(const f16x8*)(Bhs + bIdx);
            f16x8 fbl = *(const f16x8*)(Bls + bIdx);
            acc = __builtin_amdgcn_mfma_f32_32x32x16_f16(fal, fbh, acc, 0, 0, 0);
            acc = __builtin_amdgcn_mfma_f32_32x32x16_f16(fah, fbl, acc, 0, 0, 0);
            acc = __builtin_amdgcn_mfma_f32_32x32x16_f16(fah, fbh, acc, 0, 0, 0);
        }
        __syncthreads();
    }

    // ---- combine split-K partials into gbuf (C/D: col=lane&31,
    //      row=(r&3)+8*(r>>2)+4*(lane>>5))
    {
        const int col = (wc << 5) + (lane & 31);
        const int rb  = (wr << 5) + (hi << 2);
        if (kh == 0) {
            #pragma unroll
            for (int r = 0; r < 16; ++r) {
                int row = rb + (r & 3) + ((r >> 2) << 3);
                gbuf[row * 68 + col] = acc[r];
            }
        }
        __syncthreads();
        if (kh == 1) {
            #pragma unroll
            for (int r = 0; r < 16; ++r) {
                int row = rb + (r & 3) + ((r >> 2) << 3);
                gbuf[row * 68 + col] += acc[r];
            }
        }
        __syncthreads();
    }

    // ---- cell update: thread -> (j_local = tid&15, 2 b-rows)
    {
        const int jl = tid & 15;
        const int bq = tid >> 4;                 // 0..31
        const int jg = (g << 4) + jl;            // global j in [0,512)
        const float4 bv = *(const float4*)&biasI[g0 + (jl << 2)];
        float f0 = 0.0f, f1 = 0.0f;
        if (isLast) { f0 = fcw[jg]; f1 = fcw[HIDN + jg]; }

        #pragma unroll
        for (int i = 0; i < 2; ++i) {
            const int b  = (bq << 1) + i;
            const int gb = b0 + b;
            const float4 gv = *(const float4*)&gbuf[b * 68 + (jl << 2)];
            float ig = sigmoidf_(gv.x + bv.x);
            float fg = sigmoidf_(gv.y + bv.y);
            float gg = tanhf(gv.z + bv.z);
            float og = sigmoidf_(gv.w + bv.w);
            float cold = cPlane[(size_t)gb * HIDN + jg];
            float cnew = fg * cold + ig * gg;
            float hnew = og * tanhf(cnew);
            cPlane[(size_t)gb * HIDN + jg] = cnew;
            split2(hnew, &hOutH[(size_t)gb * HIDN + jg], &hOutL[(size_t)gb * HIDN + jg]);
            if (isLast) {
                float v0 = hnew * f0, v1 = hnew * f1;
                #pragma unroll
                for (int off = 8; off > 0; off >>= 1) {
                    v0 += __shfl_down(v0, off, 16);
                    v1 += __shfl_down(v1, off, 16);
                }
                if (jl == 0) {
                    atomicAdd(&params[gb * 2 + 0], v0);
                    atomicAdd(&params[gb * 2 + 1], v1);
                }
            }
        }
    }

    // ---- fused sampler: last finishing block runs the per-step tail
    if (isLast) {
        __shared__ int lastf;
        __syncthreads();
        __threadfence();
        if (tid == 0) lastf = (atomicAdd(donecnt, 1) == 255);
        __syncthreads();
        if (lastf) {
            __threadfence();
            __shared__ float red[16];
            const int mm = *maskmode;
            const float fb0 = fcb[0], fb1 = fcb[1];
            const int b = tid;                    // 512 threads = 512 batch
            float mean  = params[b * 2 + 0] + fb0;
            float sigma = softplusf_(params[b * 2 + 1] + fb1) + 1e-6f;
            out[1 + t * BB + b]           = mean;
            out[1 + TT * BB + t * BB + b] = sigma;
            float z = target[b * TT + t];
            float obs = mm
                ? (((const unsigned char*)maskraw)[b * TT + t] ? 1.0f : 0.0f)
                : (((const int*)maskraw)[b * TT + t] ? 1.0f : 0.0f);
            float nv = noise[t * BB + b];
            float dz = (z - mean) / sigma;
            float nll = 0.5f * LOG2PI + logf(sigma) + 0.5f * dz * dz;
            float v0a = nll * obs;
            float v1a = obs;
            params[b * 2 + 0] = 0.0f;
            params[b * 2 + 1] = 0.0f;
            float sample = mean + sigma * nv;
            float nxt = (obs != 0.0f) ? z : sample;
            if (t + 1 < TT) split2(nxt, &xdh[b * XLD + 0], &xdl[b * XLD + 0]);

            #pragma unroll
            for (int off = 32; off > 0; off >>= 1) {
                v0a += __shfl_down(v0a, off);
                v1a += __shfl_down(v1a, off);
            }
            if ((tid & 63) == 0) { red[(tid >> 6) * 2] = v0a; red[(tid >> 6) * 2 + 1] = v1a; }
            __syncthreads();
            if (tid == 0) {
                float s = 0.0f, so = 0.0f;
                #pragma unroll
                for (int w = 0; w < 8; ++w) { s += red[w * 2]; so += red[w * 2 + 1]; }
                float sl = (so > 0.0f) ? (s / fmaxf(so, 1.0f)) : 0.0f;
                totcnt[0] += sl;
                totcnt[1] += (so > 0.0f) ? 1.0f : 0.0f;
                if (t == TT - 1)
                    out[0] = (totcnt[1] > 0.0f) ? (totcnt[0] / totcnt[1]) : totcnt[0];
                atomicExch(donecnt, 0);
            }
            if (t + 1 < TT) {
                for (int m = tid; m < BB * COV; m += 512) {
                    int bb = m >> 2, k = m & 3;
                    split2(cov[(bb * TT + (t + 1)) * COV + k],
                           &xdh[bb * XLD + 1 + k], &xdl[bb * XLD + 1 + k]);
                }
            }
        }
    }
}

// ---------------------------------------------------------------------------
extern "C" void kernel_launch(void* const* d_in, const int* in_sizes, int n_in,
                              void* d_out, int out_size, void* d_ws, size_t ws_size,
                              hipStream_t stream) {
    const float* target       = (const float*)d_in[0];
    const float* covariates   = (const float*)d_in[1];
    const void*  maskraw      = d_in[2];
    const int*   idx          = (const int*)d_in[3];
    const float* emb_table    = (const float*)d_in[4];
    const float* fc_w         = (const float*)d_in[5];
    const float* fc_b         = (const float*)d_in[6];
    const float* noise        = (const float*)d_in[7];
    const float* Wih0 = (const float*)d_in[8];
    const float* Whh0 = (const float*)d_in[9];
    const float* bih0 = (const float*)d_in[10];
    const float* bhh0 = (const float*)d_in[11];
    const float* Wih1 = (const float*)d_in[12];
    const float* Whh1 = (const float*)d_in[13];
    const float* bih1 = (const float*)d_in[14];
    const float* bhh1 = (const float*)d_in[15];
    const float* Wih2 = (const float*)d_in[16];
    const float* Whh2 = (const float*)d_in[17];
    const float* bih2 = (const float*)d_in[18];
    const float* bhh2 = (const float*)d_in[19];
    (void)in_sizes; (void)n_in; (void)ws_size;

    const size_t PLANE = (size_t)BB * HIDN;
    const size_t NW0 = (size_t)G4 * K0TOT;
    const size_t NW1 = (size_t)G4 * K12TOT;

    _Float16* p = (_Float16*)d_ws;
    _Float16* W0h = p; p += NW0;
    _Float16* W0l = p; p += NW0;
    _Float16* W1h = p; p += NW1;
    _Float16* W1l = p; p += NW1;
    _Float16* W2h = p; p += NW1;
    _Float16* W2l = p; p += NW1;
    _Float16* Hh  = p; p += 6 * PLANE;
    _Float16* Hl  = p; p += 6 * PLANE;
    _Float16* xdh = p; p += (size_t)BB * XLD;
    _Float16* xdl = p; p += (size_t)BB * XLD;
    float* fp = (float*)p;
    float* biasI  = fp; fp += 3 * G4;
    float* C      = fp; fp += 3 * PLANE;
    float* params = fp; fp += 2 * BB;
    float* totcnt = fp; fp += 2;
    int* ip = (int*)fp;
    int* donecnt  = ip;
    int* maskmode = ip + 1;

    float* out = (float*)d_out; (void)out_size;

    pack_weights_split<<<1024, 256, 0, stream>>>(
        Wih0, Whh0, Wih1, Whh1, Wih2, Whh2,
        bih0, bhh0, bih1, bhh1, bih2, bhh2,
        W0h, W0l, W1h, W1l, W2h, W2l, biasI);
    init_state<<<1024, 256, 0, stream>>>(
        covariates, idx, emb_table, (const int*)maskraw,
        Hh, Hl, C, xdh, xdl, params, totcnt, donecnt, maskmode);

    for (int t = 0; t < TT; ++t) {
        int pi = t & 1;
        size_t curo = (pi ? 3 : 0) * PLANE;
        size_t nxto = (pi ? 0 : 3) * PLANE;
        _Float16* H0ch = Hh + curo;             _Float16* H0cl = Hl + curo;
        _Float16* H1ch = H0ch + PLANE;          _Float16* H1cl = H0cl + PLANE;
        _Float16* H2ch = H1ch + PLANE;          _Float16* H2cl = H1cl + PLANE;
        _Float16* H0nh = Hh + nxto;             _Float16* H0nl = Hl + nxto;
        _Float16* H1nh = H0nh + PLANE;          _Float16* H1nl = H0nl + PLANE;
        _Float16* H2nh = H1nh + PLANE;          _Float16* H2nl = H1nl + PLANE;

        // Layer 0: A = [xdyn(128) | h0_cur(512)], K=640
        lstm_layer<<<256, 512, 0, stream>>>(
            xdh, xdl, XLD, XLD, H0ch, H0cl, HIDN, K0TOT,
            W0h, W0l, biasI + 0 * G4, C + 0 * PLANE, H0nh, H0nl,
            0, t, params, fc_w, fc_b, target, covariates, maskraw, noise,
            xdh, xdl, totcnt, out, donecnt, maskmode);
        // Layer 1: A = [h0_new | h1_cur], K=1024
        lstm_layer<<<256, 512, 0, stream>>>(
            H0nh, H0nl, HIDN, HIDN, H1ch, H1cl, HIDN, K12TOT,
            W1h, W1l, biasI + 1 * G4, C + 1 * PLANE, H1nh, H1nl,
            0, t, params, fc_w, fc_b, target, covariates, maskraw, noise,
            xdh, xdl, totcnt, out, donecnt, maskmode);
        // Layer 2: A = [h1_new | h2_cur], K=1024, + fc partials + fused sampler
        lstm_layer<<<256, 512, 0, stream>>>(
            H1nh, H1nl, HIDN, HIDN, H2ch, H2cl, HIDN, K12TOT,
            W2h, W2l, biasI + 2 * G4, C + 2 * PLANE, H2nh, H2nl,
            1, t, params, fc_w, fc_b, target, covariates, maskraw, noise,
            xdh, xdl, totcnt, out, donecnt, maskmode);
    }
}